// Round 9
// baseline (367.922 us; speedup 1.0000x reference)
//
#include <hip/hip_runtime.h>

#define N_NODES 50000
#define M_PAD   50048            // 391 * 128
#define NBLK    196              // ceil(N_NODES/256)
#define E_EDGES 800000
#define E_TOT   (E_EDGES + N_NODES)
#define IN_C 512
#define HID 256
#define HEADS 8
#define OUT_C 64

typedef unsigned int uint;
typedef unsigned short ushort_t;
typedef __bf16 bf16x8 __attribute__((ext_vector_type(8)));
typedef float f32x4 __attribute__((ext_vector_type(4)));
typedef float f32x2 __attribute__((ext_vector_type(2)));

__device__ __forceinline__ float lrelu(float x) { return x > 0.f ? x : 0.2f * x; }

__device__ __forceinline__ unsigned short f2bf(float f) {
  uint u = __float_as_uint(f);
  u += 0x7FFF + ((u >> 16) & 1);          // RNE
  return (unsigned short)(u >> 16);
}
__device__ __forceinline__ float bflo(uint u) { return __uint_as_float(u << 16); }
__device__ __forceinline__ float bfhi(uint u) { return __uint_as_float(u & 0xFFFF0000u); }
__device__ __forceinline__ float bf2f(ushort_t u) { return __uint_as_float(((uint)u) << 16); }
__device__ __forceinline__ f32x2 unp2(uint u) {
  f32x2 r; r.x = bflo(u); r.y = bfhi(u); return r;
}

// ---------------- CSR build ----------------
__global__ void k_count(const int* __restrict__ ei, int* __restrict__ counts) {
  int e = blockIdx.x * blockDim.x + threadIdx.x;
  if (e >= E_TOT) return;
  int d = (e < E_EDGES) ? ei[E_EDGES + e] : (e - E_EDGES);
  atomicAdd(&counts[d], 1);
}

__global__ void k_bsum(const int* __restrict__ counts, int* __restrict__ bsum) {
  int i = blockIdx.x * 256 + threadIdx.x;
  int v = (i < N_NODES) ? counts[i] : 0;
  __shared__ int ws[4];
  int lane = threadIdx.x & 63, wid = threadIdx.x >> 6;
  #pragma unroll
  for (int off = 32; off; off >>= 1) v += __shfl_xor(v, off);
  if (lane == 0) ws[wid] = v;
  __syncthreads();
  if (threadIdx.x == 0) bsum[blockIdx.x] = ws[0] + ws[1] + ws[2] + ws[3];
}

__global__ void k_bscan(const int* __restrict__ bsum, int* __restrict__ boff) {
  int tid = threadIdx.x;
  int v = (tid < NBLK) ? bsum[tid] : 0;
  int lane = tid & 63, wid = tid >> 6;
  int x = v;
  #pragma unroll
  for (int off = 1; off < 64; off <<= 1) {
    int t = __shfl_up(x, off);
    if (lane >= off) x += t;
  }
  __shared__ int ws[4];
  if (lane == 63) ws[wid] = x;
  __syncthreads();
  int woff = 0;
  for (int w = 0; w < wid; w++) woff += ws[w];
  if (tid < NBLK) boff[tid] = x + woff - v;   // exclusive
}

__global__ void k_local(const int* __restrict__ counts, const int* __restrict__ boff,
                        int* __restrict__ indptr, int* __restrict__ wptr) {
  int b = blockIdx.x;
  int i = b * 256 + threadIdx.x;
  int v = (i < N_NODES) ? counts[i] : 0;
  int lane = threadIdx.x & 63, wid = threadIdx.x >> 6;
  int x = v;
  #pragma unroll
  for (int off = 1; off < 64; off <<= 1) {
    int t = __shfl_up(x, off);
    if (lane >= off) x += t;
  }
  __shared__ int ws[4];
  if (lane == 63) ws[wid] = x;
  __syncthreads();
  int woff = boff[b];
  for (int w = 0; w < wid; w++) woff += ws[w];
  int excl = woff + x - v;
  if (i < N_NODES) { indptr[i] = excl; wptr[i] = excl; }
  if (b == 0 && threadIdx.x == 0) indptr[N_NODES] = E_TOT;
}

__global__ void k_scatter(const int* __restrict__ ei, int* __restrict__ wptr,
                          int* __restrict__ csr_src) {
  int e = blockIdx.x * blockDim.x + threadIdx.x;
  if (e >= E_TOT) return;
  int s, d;
  if (e < E_EDGES) { s = ei[e]; d = ei[E_EDGES + e]; }
  else { s = d = e - E_EDGES; }
  int pos = atomicAdd(&wptr[d], 1);
  csr_src[pos] = s;
}

// ---------------- weight transposes (tiny) ----------------
__global__ void k_conv_w1(const float* __restrict__ W1, ushort_t* __restrict__ w1t) {
  int t = blockIdx.x * blockDim.x + threadIdx.x;
  if (t >= HID * IN_C) return;
  int n = t >> 9, k = t & 511;
  w1t[t] = f2bf(W1[(size_t)k * HID + n]);
}
__global__ void k_conv_w2(const float* __restrict__ W2, ushort_t* __restrict__ w2t) {
  int t = blockIdx.x * blockDim.x + threadIdx.x;
  if (t >= OUT_C * HID) return;
  int n = t >> 8, k = t & 255;
  w2t[t] = f2bf(W2[(size_t)k * OUT_C + n]);
}

// ---------------- GEMM1: h1b = bf16(x @ W1) ----------------
__global__ __launch_bounds__(512) void k_mm1(const float* __restrict__ A,
                                             const ushort_t* __restrict__ Bt,
                                             ushort_t* __restrict__ Cb) {
  __shared__ ushort_t sA[128][40];
  __shared__ ushort_t sB[256][40];
  int tid = threadIdx.x;
  int wid = tid >> 6, lane = tid & 63;
  int wm = wid >> 2, wn = wid & 3;
  int lr = lane & 15, kg = lane >> 4;
  int row0 = blockIdx.x * 128;
  f32x4 acc[4][4] = {};

  for (int k0 = 0; k0 < IN_C; k0 += 32) {
    {
      int r = tid >> 2, cs = (tid & 3) * 8;
      int gr = row0 + r;
      unsigned short v[8];
      if (gr < N_NODES) {
        const float* src = A + (size_t)gr * IN_C + k0 + cs;
        float4 f0 = *reinterpret_cast<const float4*>(src);
        float4 f1 = *reinterpret_cast<const float4*>(src + 4);
        v[0] = f2bf(f0.x); v[1] = f2bf(f0.y); v[2] = f2bf(f0.z); v[3] = f2bf(f0.w);
        v[4] = f2bf(f1.x); v[5] = f2bf(f1.y); v[6] = f2bf(f1.z); v[7] = f2bf(f1.w);
      } else {
        #pragma unroll
        for (int i = 0; i < 8; i++) v[i] = 0;
      }
      uint4 pk;
      pk.x = v[0] | ((uint)v[1] << 16); pk.y = v[2] | ((uint)v[3] << 16);
      pk.z = v[4] | ((uint)v[5] << 16); pk.w = v[6] | ((uint)v[7] << 16);
      *reinterpret_cast<uint4*>(&sA[r][cs]) = pk;
    }
    {
      int n = tid >> 1, ks = (tid & 1) * 16;
      const ushort_t* src = Bt + (size_t)n * IN_C + k0 + ks;
      uint4 v0 = *reinterpret_cast<const uint4*>(src);
      uint4 v1 = *reinterpret_cast<const uint4*>(src + 8);
      *reinterpret_cast<uint4*>(&sB[n][ks]) = v0;
      *reinterpret_cast<uint4*>(&sB[n][ks + 8]) = v1;
    }
    __syncthreads();

    bf16x8 af[4], bfr[4];
    #pragma unroll
    for (int i = 0; i < 4; i++)
      af[i] = *reinterpret_cast<const bf16x8*>(&sA[wm * 64 + i * 16 + lr][kg * 8]);
    #pragma unroll
    for (int j = 0; j < 4; j++)
      bfr[j] = *reinterpret_cast<const bf16x8*>(&sB[wn * 64 + j * 16 + lr][kg * 8]);
    #pragma unroll
    for (int i = 0; i < 4; i++)
      #pragma unroll
      for (int j = 0; j < 4; j++)
        acc[i][j] = __builtin_amdgcn_mfma_f32_16x16x32_bf16(af[i], bfr[j], acc[i][j], 0, 0, 0);
    __syncthreads();
  }

  #pragma unroll
  for (int i = 0; i < 4; i++) {
    #pragma unroll
    for (int j = 0; j < 4; j++) {
      int gc = wn * 64 + j * 16 + lr;
      #pragma unroll
      for (int q = 0; q < 4; q++) {
        int gr = row0 + wm * 64 + i * 16 + kg * 4 + q;
        if (gr < N_NODES) Cb[(size_t)gr * HID + gc] = f2bf(acc[i][j][q]);
      }
    }
  }
}

// ---------------- GEMM2: h2b = bf16(hpb_tiled @ W2) ----------------
__global__ __launch_bounds__(256) void k_mm2(const ushort_t* __restrict__ At,
                                             const ushort_t* __restrict__ Bt,
                                             ushort_t* __restrict__ Cb) {
  __shared__ ushort_t sA[128][40];
  __shared__ ushort_t sB[64][40];
  int tid = threadIdx.x;
  int wid = tid >> 6, lane = tid & 63;
  int lr = lane & 15, kg = lane >> 4;
  int row0 = blockIdx.x * 128;
  f32x4 acc[2][4] = {};

  for (int kt = 0; kt < HID / 32; ++kt) {
    {
      const ushort_t* src = At + ((size_t)blockIdx.x * 8 + kt) * 4096 + tid * 16;
      uint4 v0 = *reinterpret_cast<const uint4*>(src);
      uint4 v1 = *reinterpret_cast<const uint4*>(src + 8);
      int r = tid >> 1, ks = (tid & 1) * 16;
      *reinterpret_cast<uint4*>(&sA[r][ks]) = v0;
      *reinterpret_cast<uint4*>(&sA[r][ks + 8]) = v1;
    }
    if (tid < 128) {
      int n = tid >> 1, ks = (tid & 1) * 16;
      const ushort_t* src = Bt + (size_t)n * HID + kt * 32 + ks;
      uint4 v0 = *reinterpret_cast<const uint4*>(src);
      uint4 v1 = *reinterpret_cast<const uint4*>(src + 8);
      *reinterpret_cast<uint4*>(&sB[n][ks]) = v0;
      *reinterpret_cast<uint4*>(&sB[n][ks + 8]) = v1;
    }
    __syncthreads();

    bf16x8 af[2], bfr[4];
    #pragma unroll
    for (int i = 0; i < 2; i++)
      af[i] = *reinterpret_cast<const bf16x8*>(&sA[wid * 32 + i * 16 + lr][kg * 8]);
    #pragma unroll
    for (int j = 0; j < 4; j++)
      bfr[j] = *reinterpret_cast<const bf16x8*>(&sB[j * 16 + lr][kg * 8]);
    #pragma unroll
    for (int i = 0; i < 2; i++)
      #pragma unroll
      for (int j = 0; j < 4; j++)
        acc[i][j] = __builtin_amdgcn_mfma_f32_16x16x32_bf16(af[i], bfr[j], acc[i][j], 0, 0, 0);
    __syncthreads();
  }

  #pragma unroll
  for (int i = 0; i < 2; i++) {
    #pragma unroll
    for (int j = 0; j < 4; j++) {
      int gc = j * 16 + lr;
      #pragma unroll
      for (int q = 0; q < 4; q++) {
        int gr = row0 + wid * 32 + i * 16 + kg * 4 + q;
        if (gr < N_NODES) Cb[(size_t)gr * OUT_C + gc] = f2bf(acc[i][j][q]);
      }
    }
  }
}

// ---------------- attention logits ----------------
__global__ void k_alpha1(const ushort_t* __restrict__ h1b, const float* __restrict__ a_src,
                         const float* __restrict__ a_dst, float* __restrict__ as1,
                         float* __restrict__ ad1) {
  int t = blockIdx.x * blockDim.x + threadIdx.x;
  if (t >= N_NODES * HEADS) return;
  int n = t >> 3, h = t & 7;
  const ushort_t* row = h1b + (size_t)n * HID + h * 32;
  const float* asr = a_src + h * 32;
  const float* adr = a_dst + h * 32;
  float ss = 0.f, sd = 0.f;
  #pragma unroll
  for (int c = 0; c < 32; c += 8) {
    uint4 rv = *reinterpret_cast<const uint4*>(row + c);
    uint uu[4] = {rv.x, rv.y, rv.z, rv.w};
    #pragma unroll
    for (int q = 0; q < 4; q++) {
      float f0 = bflo(uu[q]), f1 = bfhi(uu[q]);
      ss += f0 * asr[c + q * 2] + f1 * asr[c + q * 2 + 1];
      sd += f0 * adr[c + q * 2] + f1 * adr[c + q * 2 + 1];
    }
  }
  as1[t] = ss;
  ad1[t] = sd;
}

__global__ void k_alpha2(const ushort_t* __restrict__ h2b, const float* __restrict__ a_src,
                         const float* __restrict__ a_dst, float* __restrict__ as2,
                         float* __restrict__ ad2) {
  int wave = threadIdx.x >> 6, lane = threadIdx.x & 63;
  int n = blockIdx.x * 4 + wave;
  if (n >= N_NODES) return;
  float v = bf2f(h2b[(size_t)n * OUT_C + lane]);
  float ss = v * a_src[lane];
  float sd = v * a_dst[lane];
  #pragma unroll
  for (int off = 32; off; off >>= 1) {
    ss += __shfl_xor(ss, off);
    sd += __shfl_xor(sd, off);
  }
  if (lane == 0) { as2[n] = ss; ad2[n] = sd; }
}

// ---------------- layer-1 aggregation: channel-quarter blocks, XCD-pinned ----------------
// grid = 6250 chunks * 8 slots; slot = bid&7 -> XCD slot (bid%8 round-robin);
// quarter q = slot>>1 (XCDs {2q,2q+1}); node = chunk*8 + (slot&1)*4 + wave.
// Wave: 8 edges in parallel (eslot=lane>>3), 8 ch/lane (cl=lane&7): 128 B/edge.
__global__ __launch_bounds__(256) void k_agg1(const ushort_t* __restrict__ h1b,
                                              const int* __restrict__ indptr,
                                              const int* __restrict__ csr_src,
                                              const float* __restrict__ as1,
                                              const float* __restrict__ ad1,
                                              const float* __restrict__ b1,
                                              ushort_t* __restrict__ hpb) {
  int chunk = blockIdx.x >> 3, slot = blockIdx.x & 7;
  int q = slot >> 1, sub = slot & 1;
  int wave = threadIdx.x >> 6, lane = threadIdx.x & 63;
  int node = chunk * 8 + sub * 4 + wave;          // 6250*8 == 50000 exact
  int beg = indptr[node], end = indptr[node + 1];
  int eslot = lane >> 3, cl = lane & 7;
  int h = q * 2 + (cl >> 2);
  float adst = ad1[node * 8 + h];
  const ushort_t* hq = h1b + q * 64 + cl * 8;     // this lane's 16 B within a row

  f32x2 a0 = {0.f, 0.f}, a1 = {0.f, 0.f}, a2 = {0.f, 0.f}, a3 = {0.f, 0.f};
  float dsum = 0.f;
  for (int e = beg + eslot; e < end; e += 8) {
    int s = csr_src[e];
    float l = as1[s * 8 + h];
    uint4 rv = *reinterpret_cast<const uint4*>(&hq[(size_t)s * HID]);
    float w = __expf(lrelu(l + adst));
    a0 += w * unp2(rv.x); a1 += w * unp2(rv.y);
    a2 += w * unp2(rv.z); a3 += w * unp2(rv.w);
    dsum += w;
  }
  // reduce across 8 edge-slots (lane bits 3,4,5)
  #pragma unroll
  for (int off = 8; off <= 32; off <<= 1) {
    a0.x += __shfl_xor(a0.x, off); a0.y += __shfl_xor(a0.y, off);
    a1.x += __shfl_xor(a1.x, off); a1.y += __shfl_xor(a1.y, off);
    a2.x += __shfl_xor(a2.x, off); a2.y += __shfl_xor(a2.y, off);
    a3.x += __shfl_xor(a3.x, off); a3.y += __shfl_xor(a3.y, off);
    dsum += __shfl_xor(dsum, off);
  }
  float inv = 1.f / (dsum + 1e-16f);

  if (eslot == 0) {
    float acc[8] = {a0.x, a0.y, a1.x, a1.y, a2.x, a2.y, a3.x, a3.y};
    int c0 = q * 64 + cl * 8;
    unsigned short ob[8];
    #pragma unroll
    for (int j = 0; j < 8; j++) {
      float o = acc[j] * inv + b1[c0 + j];
      o = o > 0.f ? o : expm1f(o);
      ob[j] = f2bf(o);
    }
    uint4 pk;
    pk.x = ob[0] | ((uint)ob[1] << 16); pk.y = ob[2] | ((uint)ob[3] << 16);
    pk.z = ob[4] | ((uint)ob[5] << 16); pk.w = ob[6] | ((uint)ob[7] << 16);
    int kt = 2 * q + (cl >> 2);
    size_t addr = ((size_t)(node >> 7) * 8 + kt) * 4096 + (size_t)(node & 127) * 32 + (cl & 3) * 8;
    *reinterpret_cast<uint4*>(&hpb[addr]) = pk;
  }
}

// ---------------- layer-2 aggregation: bf16 gather, channel-half blocks, XCD-pinned ----------------
// grid = 3125 chunks * 8 slots; half = slot>>2 (XCDs {0..3}/{4..7});
// node = chunk*16 + (slot&3)*4 + wave. 16 edges in parallel (eslot=lane>>2), 8 ch/lane.
__global__ __launch_bounds__(256) void k_agg2(const ushort_t* __restrict__ h2b,
                                              const int* __restrict__ indptr,
                                              const int* __restrict__ csr_src,
                                              const float* __restrict__ as2,
                                              const float* __restrict__ ad2,
                                              const float* __restrict__ b2,
                                              float* __restrict__ out) {
  int chunk = blockIdx.x >> 3, slot = blockIdx.x & 7;
  int half = slot >> 2, sub = slot & 3;
  int wave = threadIdx.x >> 6, lane = threadIdx.x & 63;
  int node = chunk * 16 + sub * 4 + wave;         // 3125*16 == 50000 exact
  int beg = indptr[node], end = indptr[node + 1];
  int eslot = lane >> 2, cl = lane & 3;
  float adst = ad2[node];
  const ushort_t* hq = h2b + half * 32 + cl * 8;

  f32x2 a0 = {0.f, 0.f}, a1 = {0.f, 0.f}, a2 = {0.f, 0.f}, a3 = {0.f, 0.f};
  float dsum = 0.f;
  for (int e = beg + eslot; e < end; e += 16) {
    int s = csr_src[e];
    float l = as2[s];
    uint4 rv = *reinterpret_cast<const uint4*>(&hq[(size_t)s * OUT_C]);
    float w = __expf(lrelu(l + adst));
    a0 += w * unp2(rv.x); a1 += w * unp2(rv.y);
    a2 += w * unp2(rv.z); a3 += w * unp2(rv.w);
    dsum += w;
  }
  // reduce across 16 edge-slots (lane bits 2..5)
  #pragma unroll
  for (int off = 4; off <= 32; off <<= 1) {
    a0.x += __shfl_xor(a0.x, off); a0.y += __shfl_xor(a0.y, off);
    a1.x += __shfl_xor(a1.x, off); a1.y += __shfl_xor(a1.y, off);
    a2.x += __shfl_xor(a2.x, off); a2.y += __shfl_xor(a2.y, off);
    a3.x += __shfl_xor(a3.x, off); a3.y += __shfl_xor(a3.y, off);
    dsum += __shfl_xor(dsum, off);
  }
  float inv = 1.f / (dsum + 1e-16f);

  if (eslot == 0) {
    int c0 = half * 32 + cl * 8;
    float4 o0 = {a0.x * inv + b2[c0],     a0.y * inv + b2[c0 + 1],
                 a1.x * inv + b2[c0 + 2], a1.y * inv + b2[c0 + 3]};
    float4 o1 = {a2.x * inv + b2[c0 + 4], a2.y * inv + b2[c0 + 5],
                 a3.x * inv + b2[c0 + 6], a3.y * inv + b2[c0 + 7]};
    *reinterpret_cast<float4*>(&out[(size_t)node * OUT_C + c0]) = o0;
    *reinterpret_cast<float4*>(&out[(size_t)node * OUT_C + c0 + 4]) = o1;
  }
}

extern "C" void kernel_launch(void* const* d_in, const int* in_sizes, int n_in,
                              void* d_out, int out_size, void* d_ws, size_t ws_size,
                              hipStream_t stream) {
  const float* x     = (const float*)d_in[0];
  const int*   ei    = (const int*)d_in[1];
  const float* W1    = (const float*)d_in[2];
  const float* asrc1 = (const float*)d_in[3];
  const float* adst1 = (const float*)d_in[4];
  const float* b1    = (const float*)d_in[5];
  const float* W2    = (const float*)d_in[6];
  const float* asrc2 = (const float*)d_in[7];
  const float* adst2 = (const float*)d_in[8];
  const float* b2    = (const float*)d_in[9];
  float* out = (float*)d_out;

  char* p = (char*)d_ws;
  size_t off = 0;
  auto take = [&](size_t bytes) -> void* {
    void* r = p + off;
    off += (bytes + 255) & ~(size_t)255;
    return r;
  };
  ushort_t* h1b  = (ushort_t*)take((size_t)N_NODES * HID * 2);
  ushort_t* hpb  = (ushort_t*)take((size_t)(M_PAD / 128) * 8 * 4096 * 2);
  ushort_t* h2b  = (ushort_t*)take((size_t)N_NODES * OUT_C * 2);
  float*    as1  = (float*)take((size_t)N_NODES * HEADS * 4);
  float*    ad1  = (float*)take((size_t)N_NODES * HEADS * 4);
  float*    as2  = (float*)take((size_t)N_NODES * 4);
  float*    ad2  = (float*)take((size_t)N_NODES * 4);
  int* counts = (int*)take((size_t)N_NODES * 4);
  int* indptr = (int*)take((size_t)(N_NODES + 1) * 4);
  int* wptr   = (int*)take((size_t)(N_NODES + 1) * 4);
  int* bsum   = (int*)take((size_t)NBLK * 4);
  int* boff   = (int*)take((size_t)NBLK * 4);
  int* csr    = (int*)take((size_t)E_TOT * 4);
  ushort_t* w1t = (ushort_t*)take((size_t)IN_C * HID * 2);
  ushort_t* w2t = (ushort_t*)take((size_t)HID * OUT_C * 2);

  // CSR build (parallel scan)
  hipMemsetAsync(counts, 0, (size_t)N_NODES * 4, stream);
  k_count<<<(E_TOT + 255) / 256, 256, 0, stream>>>(ei, counts);
  k_bsum<<<NBLK, 256, 0, stream>>>(counts, bsum);
  k_bscan<<<1, 256, 0, stream>>>(bsum, boff);
  k_local<<<NBLK, 256, 0, stream>>>(counts, boff, indptr, wptr);
  k_scatter<<<(E_TOT + 255) / 256, 256, 0, stream>>>(ei, wptr, csr);

  // weight transposes
  k_conv_w1<<<(HID * IN_C + 255) / 256, 256, 0, stream>>>(W1, w1t);
  k_conv_w2<<<(OUT_C * HID + 255) / 256, 256, 0, stream>>>(W2, w2t);

  // layer 1
  k_mm1<<<M_PAD / 128, 512, 0, stream>>>(x, w1t, h1b);
  k_alpha1<<<(N_NODES * HEADS + 255) / 256, 256, 0, stream>>>(h1b, asrc1, adst1, as1, ad1);
  k_agg1<<<(N_NODES / 8) * 8, 256, 0, stream>>>(h1b, indptr, csr, as1, ad1, b1, hpb);

  // layer 2
  k_mm2<<<M_PAD / 128, 256, 0, stream>>>(hpb, w2t, h2b);
  k_alpha2<<<(N_NODES + 3) / 4, 256, 0, stream>>>(h2b, asrc2, adst2, as2, ad2);
  k_agg2<<<(N_NODES / 16) * 8, 256, 0, stream>>>(h2b, indptr, csr, as2, ad2, b2, out);
}